// Round 8
// baseline (204.268 us; speedup 1.0000x reference)
//
#include <hip/hip_runtime.h>
#include <hip/hip_bf16.h>

typedef __hip_bfloat16 bf16;
typedef __attribute__((ext_vector_type(8))) short short8;
typedef __attribute__((ext_vector_type(4))) float f32x4;

#define NB    20000
#define BATCH 2
#define HDIM  128
#define KNBR  32
#define NCLS  40
#define NLAYER 3
#define BM    64          // rows (nodes) per block tile
#define LDP   136         // padded LDS row stride (bf16 elems): 272 B, 16B-aligned
#define NTILES 625        // flattened tiles over 40000 nodes
#define LGRID  632        // 79*8, batch-XCD swizzled with guards

__device__ __forceinline__ short f2bf(float v) {
    return __builtin_bit_cast(short, __float2bfloat16(v));
}
__device__ __forceinline__ float blo(unsigned u) { return __builtin_bit_cast(float, u << 16); }
__device__ __forceinline__ float bhi(unsigned u) { return __builtin_bit_cast(float, u & 0xffff0000u); }

// ---------------- weight pre-pack: f32 [K][N] -> bf16 fragment layout ----------------
__global__ void pack_weights(const float* __restrict__ Wemb, const float* __restrict__ gW,
                             const float* __restrict__ gB, const float* __restrict__ W1,
                             const float* __restrict__ W2, short* __restrict__ pw) {
    const int idx = blockIdx.x * 256 + threadIdx.x;
    if (idx < 8 * 16384) {
        const int m = idx >> 14, e = idx & 16383;
        const float* src = (m == 0) ? Wemb
                         : (m <= 3) ? gW + (size_t)(m - 1) * 16384
                         : (m <= 6) ? gB + (size_t)(m - 4) * 16384
                         : W1;
        const int k = e >> 7, n = e & 127;
        pw[m * 16384 + (((k >> 3) * 128 + n) << 3) + (k & 7)] = f2bf(src[e]);
    } else {
        const int e = idx - 8 * 16384;
        if (e < 128 * NCLS) {
            const int k = e / NCLS, n = e - k * NCLS;
            pw[8 * 16384 + ((k >> 3) * NCLS + n) * 8 + (k & 7)] = f2bf(W2[e]);
        }
    }
}

// ---------------- embed: h0 = (x @ Wemb) / rowsum(x), rowsum via ones-MFMA ----------------
__global__ __launch_bounds__(512, 4) void embed_gemm(const float* __restrict__ x,
                                                     const short* __restrict__ pwE,
                                                     bf16* __restrict__ h0) {
    __shared__ short sx[BM * LDP];
    const int t = threadIdx.x;
    const int row0 = blockIdx.x * BM;

    {
        const int r = t >> 3, fs = (t & 7) * 16;
        const float4* p = (const float4*)(x + (size_t)(row0 + r) * HDIM + fs);
        float4 v[4];
#pragma unroll
        for (int i = 0; i < 4; ++i) v[i] = p[i];
        const float* vf = (const float*)v;
        unsigned* dst = (unsigned*)(sx + r * LDP + fs);
#pragma unroll
        for (int i = 0; i < 8; ++i) {
            unsigned lo = (unsigned)(unsigned short)f2bf(vf[2 * i]);
            unsigned hi = (unsigned)(unsigned short)f2bf(vf[2 * i + 1]);
            dst[i] = lo | (hi << 16);
        }
    }
    __syncthreads();

    const int w = t >> 6, l = t & 63;
    const int m16 = l & 15, quad = l >> 4;
    const int col = w * 16 + m16;

    short8 ones;
#pragma unroll
    for (int j = 0; j < 8; ++j) ones[j] = (short)0x3F80;  // bf16 1.0

    short8 wf[4];
#pragma unroll
    for (int q = 0; q < 4; ++q)
        wf[q] = *(const short8*)(pwE + (((q * 4 + quad) * 128 + col) << 3));

    f32x4 acc[4] = {}, rsum[4] = {};
#pragma unroll
    for (int q = 0; q < 4; ++q)
#pragma unroll
        for (int mt = 0; mt < 4; ++mt) {
            short8 a = *(const short8*)(sx + (mt * 16 + m16) * LDP + q * 32 + quad * 8);
            acc[mt]  = __builtin_amdgcn_mfma_f32_16x16x32_bf16(a, wf[q], acc[mt], 0, 0, 0);
            rsum[mt] = __builtin_amdgcn_mfma_f32_16x16x32_bf16(a, ones,  rsum[mt], 0, 0, 0);
        }

#pragma unroll
    for (int mt = 0; mt < 4; ++mt)
#pragma unroll
        for (int r = 0; r < 4; ++r) {
            const int rr = row0 + mt * 16 + quad * 4 + r;
            h0[(size_t)rr * HDIM + col] = __float2bfloat16(acc[mt][r] / rsum[mt][r]);
        }
}

// ---------------- GCN layer: h_out = relu(NG@W + H@B) ----------------
// XCD swizzle as round 7.  Gather: 2 feature phases (L2-tight), k-loop
// software-pipelined 4-ahead (≈8 loads in flight).  launch_bounds(512,6)
// caps VGPR at 85 so LDS (42.8 KB -> 3 blocks/CU) is the binding limit.
__global__ __launch_bounds__(512, 6) void layer_gemm(const bf16* __restrict__ h_in,
                                                     const int* __restrict__ nidx,
                                                     const int* __restrict__ vlen,
                                                     const short* __restrict__ pwW,
                                                     const short* __restrict__ pwB,
                                                     bf16* __restrict__ h_out) {
    __shared__ int   sidx[BM * KNBR];   // 8 KB
    __shared__ short sng[BM * LDP];     // 17.4 KB
    __shared__ short sh[BM * LDP];      // 17.4 KB

    const int slot = blockIdx.x & 7;
    const int half = slot >> 2;
    const int idx  = (blockIdx.x >> 3) * 4 + (slot & 3);
    int tile;
    if (half == 0) { if (idx > 312) return; tile = idx; }
    else           { if (idx > 311) return; tile = idx + 313; }

    const int t = threadIdx.x;
    const int row0 = tile * BM;

    ((int4*)sidx)[t] = ((const int4*)(nidx + (size_t)row0 * KNBR))[t];
    {
        const int r = t >> 3, fs = (t & 7) * 16;
        const uint4* p = (const uint4*)(h_in + (size_t)(row0 + r) * HDIM + fs);
        uint4 a = p[0], b = p[1];
        uint4* d = (uint4*)(sh + r * LDP + fs);
        d[0] = a; d[1] = b;
    }
    __syncthreads();

    // ---- gather: 8 threads/node, 8 features, 2 phases, 4-ahead pipeline ----
    {
        const int node = t >> 3;
        const int fs8 = (t & 7) * 8;
        const int g = row0 + node;
        const bf16* hb = h_in + (size_t)((g >= NB) ? NB : 0) * HDIM;
        const int* ip = sidx + node * KNBR;
        int vl = vlen[g]; if (vl == 0) vl = 1;
        const float inv = 1.0f / (float)vl;

#pragma unroll
        for (int fh = 0; fh < 2; ++fh) {
            const int fs = fh * 64 + fs8;
            float acc[8];
#pragma unroll
            for (int i = 0; i < 8; ++i) acc[i] = 0.0f;

            uint4 u[4], v[4];
#pragma unroll
            for (int j = 0; j < 4; ++j)
                u[j] = *(const uint4*)(hb + (size_t)ip[j] * HDIM + fs);
#pragma unroll
            for (int kb = 0; kb < KNBR; kb += 4) {
                if (kb + 4 < KNBR) {
#pragma unroll
                    for (int j = 0; j < 4; ++j)
                        v[j] = *(const uint4*)(hb + (size_t)ip[kb + 4 + j] * HDIM + fs);
                }
#pragma unroll
                for (int j = 0; j < 4; ++j) {
                    const uint4 uu = u[j];
                    acc[0] += blo(uu.x); acc[1] += bhi(uu.x);
                    acc[2] += blo(uu.y); acc[3] += bhi(uu.y);
                    acc[4] += blo(uu.z); acc[5] += bhi(uu.z);
                    acc[6] += blo(uu.w); acc[7] += bhi(uu.w);
                }
#pragma unroll
                for (int j = 0; j < 4; ++j) u[j] = v[j];
            }

            unsigned* dst = (unsigned*)(sng + node * LDP + fs);
#pragma unroll
            for (int i = 0; i < 4; ++i) {
                unsigned lo = (unsigned)(unsigned short)f2bf(acc[2 * i] * inv);
                unsigned hi = (unsigned)(unsigned short)f2bf(acc[2 * i + 1] * inv);
                dst[i] = lo | (hi << 16);
            }
            __syncthreads();   // phase alignment keeps L2 working set tight
        }
    }

    // ---- MFMA: acc = NG@W + H@B (one 16-col slice per wave) ----
    const int w = t >> 6, l = t & 63;
    const int m16 = l & 15, quad = l >> 4;
    const int col = w * 16 + m16;

    short8 wfW[4], wfB[4];
#pragma unroll
    for (int q = 0; q < 4; ++q) {
        const int off = ((q * 4 + quad) * 128 + col) << 3;
        wfW[q] = *(const short8*)(pwW + off);
        wfB[q] = *(const short8*)(pwB + off);
    }

    f32x4 acc[4] = {};
#pragma unroll
    for (int q = 0; q < 4; ++q)
#pragma unroll
        for (int mt = 0; mt < 4; ++mt) {
            short8 aN = *(const short8*)(sng + (mt * 16 + m16) * LDP + q * 32 + quad * 8);
            short8 aH = *(const short8*)(sh  + (mt * 16 + m16) * LDP + q * 32 + quad * 8);
            acc[mt] = __builtin_amdgcn_mfma_f32_16x16x32_bf16(aN, wfW[q], acc[mt], 0, 0, 0);
            acc[mt] = __builtin_amdgcn_mfma_f32_16x16x32_bf16(aH, wfB[q], acc[mt], 0, 0, 0);
        }

#pragma unroll
    for (int mt = 0; mt < 4; ++mt)
#pragma unroll
        for (int r = 0; r < 4; ++r) {
            const int rr = row0 + mt * 16 + quad * 4 + r;
            h_out[(size_t)rr * HDIM + col] = __float2bfloat16(fmaxf(acc[mt][r], 0.0f));
        }
}

// ---------------- classifier: softmax(relu(h@W1+b1)@W2 + b2) ----------------
__global__ __launch_bounds__(512, 4) void cls_gemm(const bf16* __restrict__ h,
                                                   const short* __restrict__ pwW1,
                                                   const float* __restrict__ b1,
                                                   const short* __restrict__ pwW2,
                                                   const float* __restrict__ b2,
                                                   float* __restrict__ out) {
    __shared__ short sh[BM * LDP];
    __shared__ short sz[BM * LDP];
    __shared__ float lg[BM * 48];
    const int t = threadIdx.x;
    const int row0 = blockIdx.x * BM;

    {
        const int r = t >> 3, fs = (t & 7) * 16;
        const uint4* p = (const uint4*)(h + (size_t)(row0 + r) * HDIM + fs);
        uint4 a = p[0], b = p[1];
        uint4* d = (uint4*)(sh + r * LDP + fs);
        d[0] = a; d[1] = b;
    }
    __syncthreads();

    const int w = t >> 6, l = t & 63;
    const int m16 = l & 15, quad = l >> 4;
    const int col = w * 16 + m16;

    // ---- stage 1: z = relu(h @ W1 + b1) -> LDS ----
    {
        short8 wf[4];
#pragma unroll
        for (int q = 0; q < 4; ++q)
            wf[q] = *(const short8*)(pwW1 + (((q * 4 + quad) * 128 + col) << 3));
        f32x4 acc[4] = {};
#pragma unroll
        for (int q = 0; q < 4; ++q)
#pragma unroll
            for (int mt = 0; mt < 4; ++mt) {
                short8 a = *(const short8*)(sh + (mt * 16 + m16) * LDP + q * 32 + quad * 8);
                acc[mt] = __builtin_amdgcn_mfma_f32_16x16x32_bf16(a, wf[q], acc[mt], 0, 0, 0);
            }
        const float bias = b1[col];
#pragma unroll
        for (int mt = 0; mt < 4; ++mt)
#pragma unroll
            for (int r = 0; r < 4; ++r)
                sz[(mt * 16 + quad * 4 + r) * LDP + col] = f2bf(fmaxf(acc[mt][r] + bias, 0.0f));
    }
    __syncthreads();

    // ---- stage 2: logits = z @ W2 + b2 (waves 0..2 cover 40 cols) ----
    if (w < 3) {
        const bool valid = (col < NCLS);
        short8 wf[4];
#pragma unroll
        for (int q = 0; q < 4; ++q) {
            if (valid) wf[q] = *(const short8*)(pwW2 + (((q * 4 + quad) * NCLS + col) << 3));
            else {
#pragma unroll
                for (int j = 0; j < 8; ++j) wf[q][j] = 0;
            }
        }
        f32x4 acc[4] = {};
#pragma unroll
        for (int q = 0; q < 4; ++q)
#pragma unroll
            for (int mt = 0; mt < 4; ++mt) {
                short8 a = *(const short8*)(sz + (mt * 16 + m16) * LDP + q * 32 + quad * 8);
                acc[mt] = __builtin_amdgcn_mfma_f32_16x16x32_bf16(a, wf[q], acc[mt], 0, 0, 0);
            }
        if (valid) {
            const float bias = b2[col];
#pragma unroll
            for (int mt = 0; mt < 4; ++mt)
#pragma unroll
                for (int r = 0; r < 4; ++r)
                    lg[(mt * 16 + quad * 4 + r) * 48 + col] = acc[mt][r] + bias;
        }
    }
    __syncthreads();

    // ---- softmax per row ----
    if (t < BM) {
        float* row = lg + t * 48;
        float m = row[0];
        for (int c = 1; c < NCLS; ++c) m = fmaxf(m, row[c]);
        float s = 0.0f;
        for (int c = 0; c < NCLS; ++c) { float e = expf(row[c] - m); row[c] = e; s += e; }
        const float inv = 1.0f / s;
        for (int c = 0; c < NCLS; ++c) row[c] *= inv;
    }
    __syncthreads();

    for (int i = t; i < BM * NCLS; i += 512) {
        const int r = i / NCLS, c = i - r * NCLS;
        out[(size_t)row0 * NCLS + i] = lg[r * 48 + c];
    }
}

extern "C" void kernel_launch(void* const* d_in, const int* in_sizes, int n_in,
                              void* d_out, int out_size, void* d_ws, size_t ws_size,
                              hipStream_t stream) {
    const float* x    = (const float*)d_in[0];
    const int*  nidx  = (const int*)  d_in[1];
    const int*  vlen  = (const int*)  d_in[2];
    const float* Wemb = (const float*)d_in[3];
    const float* gW   = (const float*)d_in[4];
    const float* gB   = (const float*)d_in[5];
    const float* W1   = (const float*)d_in[6];
    const float* b1   = (const float*)d_in[7];
    const float* W2   = (const float*)d_in[8];
    const float* b2   = (const float*)d_in[9];
    float* out = (float*)d_out;

    const int nodes = BATCH * NB;           // 40000
    bf16* h0 = (bf16*)d_ws;
    bf16* h1 = h0 + (size_t)nodes * HDIM;
    short* pw = (short*)(h1 + (size_t)nodes * HDIM);   // 272 KB packed weights
    const short* pwE  = pw;
    const short* pwW1 = pw + 7 * 16384;
    const short* pwW2 = pw + 8 * 16384;

    pack_weights<<<(8 * 16384 + 128 * NCLS + 255) / 256, 256, 0, stream>>>(Wemb, gW, gB, W1, W2, pw);
    embed_gemm<<<NTILES, 512, 0, stream>>>(x, pwE, h0);

    for (int lyr = 0; lyr < NLAYER; ++lyr) {
        layer_gemm<<<LGRID, 512, 0, stream>>>(h0, nidx, vlen,
                                              pw + (size_t)(1 + lyr) * 16384,
                                              pw + (size_t)(4 + lyr) * 16384,
                                              h1);
        bf16* tmp = h0; h0 = h1; h1 = tmp;
    }

    cls_gemm<<<NTILES, 512, 0, stream>>>(h0, pwW1, b1, pwW2, b2, out);
}

// Round 9
// 202.440 us; speedup vs baseline: 1.0090x; 1.0090x over previous
//
#include <hip/hip_runtime.h>
#include <hip/hip_bf16.h>

typedef __hip_bfloat16 bf16;
typedef __attribute__((ext_vector_type(8))) short short8;
typedef __attribute__((ext_vector_type(4))) float f32x4;

#define NB    20000
#define BATCH 2
#define HDIM  128
#define KNBR  32
#define NCLS  40
#define NLAYER 3
#define BM    64          // rows (nodes) per block tile
#define LDP   136         // padded LDS row stride (bf16 elems): 272 B, 16B-aligned
#define NTILES 625        // flattened tiles over 40000 nodes
#define LGRID  632        // 79*8, batch-XCD swizzled with guards

__device__ __forceinline__ short f2bf(float v) {
    return __builtin_bit_cast(short, __float2bfloat16(v));
}
__device__ __forceinline__ float blo(unsigned u) { return __builtin_bit_cast(float, u << 16); }
__device__ __forceinline__ float bhi(unsigned u) { return __builtin_bit_cast(float, u & 0xffff0000u); }

// ---------------- weight pre-pack: f32 [K][N] -> bf16 fragment layout ----------------
__global__ void pack_weights(const float* __restrict__ Wemb, const float* __restrict__ gW,
                             const float* __restrict__ gB, const float* __restrict__ W1,
                             const float* __restrict__ W2, short* __restrict__ pw) {
    const int idx = blockIdx.x * 256 + threadIdx.x;
    if (idx < 8 * 16384) {
        const int m = idx >> 14, e = idx & 16383;
        const float* src = (m == 0) ? Wemb
                         : (m <= 3) ? gW + (size_t)(m - 1) * 16384
                         : (m <= 6) ? gB + (size_t)(m - 4) * 16384
                         : W1;
        const int k = e >> 7, n = e & 127;
        pw[m * 16384 + (((k >> 3) * 128 + n) << 3) + (k & 7)] = f2bf(src[e]);
    } else {
        const int e = idx - 8 * 16384;
        if (e < 128 * NCLS) {
            const int k = e / NCLS, n = e - k * NCLS;
            pw[8 * 16384 + ((k >> 3) * NCLS + n) * 8 + (k & 7)] = f2bf(W2[e]);
        }
    }
}

// ---------------- embed: h0 = (x @ Wemb) / rowsum(x), rowsum via ones-MFMA ----------------
__global__ __launch_bounds__(512, 4) void embed_gemm(const float* __restrict__ x,
                                                     const short* __restrict__ pwE,
                                                     bf16* __restrict__ h0) {
    __shared__ short sx[BM * LDP];
    const int t = threadIdx.x;
    const int row0 = blockIdx.x * BM;

    {
        const int r = t >> 3, fs = (t & 7) * 16;
        const float4* p = (const float4*)(x + (size_t)(row0 + r) * HDIM + fs);
        float4 v[4];
#pragma unroll
        for (int i = 0; i < 4; ++i) v[i] = p[i];
        const float* vf = (const float*)v;
        unsigned* dst = (unsigned*)(sx + r * LDP + fs);
#pragma unroll
        for (int i = 0; i < 8; ++i) {
            unsigned lo = (unsigned)(unsigned short)f2bf(vf[2 * i]);
            unsigned hi = (unsigned)(unsigned short)f2bf(vf[2 * i + 1]);
            dst[i] = lo | (hi << 16);
        }
    }
    __syncthreads();

    const int w = t >> 6, l = t & 63;
    const int m16 = l & 15, quad = l >> 4;
    const int col = w * 16 + m16;

    short8 ones;
#pragma unroll
    for (int j = 0; j < 8; ++j) ones[j] = (short)0x3F80;  // bf16 1.0

    short8 wf[4];
#pragma unroll
    for (int q = 0; q < 4; ++q)
        wf[q] = *(const short8*)(pwE + (((q * 4 + quad) * 128 + col) << 3));

    f32x4 acc[4] = {}, rsum[4] = {};
#pragma unroll
    for (int q = 0; q < 4; ++q)
#pragma unroll
        for (int mt = 0; mt < 4; ++mt) {
            short8 a = *(const short8*)(sx + (mt * 16 + m16) * LDP + q * 32 + quad * 8);
            acc[mt]  = __builtin_amdgcn_mfma_f32_16x16x32_bf16(a, wf[q], acc[mt], 0, 0, 0);
            rsum[mt] = __builtin_amdgcn_mfma_f32_16x16x32_bf16(a, ones,  rsum[mt], 0, 0, 0);
        }

#pragma unroll
    for (int mt = 0; mt < 4; ++mt)
#pragma unroll
        for (int r = 0; r < 4; ++r) {
            const int rr = row0 + mt * 16 + quad * 4 + r;
            h0[(size_t)rr * HDIM + col] = __float2bfloat16(acc[mt][r] / rsum[mt][r]);
        }
}

// ---------------- GCN layer: h_out = relu(NG@W + H@B) ----------------
// XCD swizzle as round 7.  Gather: round-7 simple unroll-4 loop (proven).
// Register diet for (512,6) => 24 waves/CU without spills:
//   - no sh staging: H-operand fragments read directly from global (L2-hot)
//   - weight fragments loaded per-q inside the MFMA loop (8 live regs, not 32)
__global__ __launch_bounds__(512, 6) void layer_gemm(const bf16* __restrict__ h_in,
                                                     const int* __restrict__ nidx,
                                                     const int* __restrict__ vlen,
                                                     const short* __restrict__ pwW,
                                                     const short* __restrict__ pwB,
                                                     bf16* __restrict__ h_out) {
    __shared__ int   sidx[BM * KNBR];   // 8 KB
    __shared__ short sng[BM * LDP];     // 17.4 KB

    const int slot = blockIdx.x & 7;
    const int half = slot >> 2;
    const int idx  = (blockIdx.x >> 3) * 4 + (slot & 3);
    int tile;
    if (half == 0) { if (idx > 312) return; tile = idx; }
    else           { if (idx > 311) return; tile = idx + 313; }

    const int t = threadIdx.x;
    const int row0 = tile * BM;

    ((int4*)sidx)[t] = ((const int4*)(nidx + (size_t)row0 * KNBR))[t];
    __syncthreads();

    // ---- gather: 8 threads/node, 8 features, 2 phases (round-7 form) ----
    {
        const int node = t >> 3;
        const int fs8 = (t & 7) * 8;
        const int g = row0 + node;
        const bf16* hb = h_in + (size_t)((g >= NB) ? NB : 0) * HDIM;
        const int* ip = sidx + node * KNBR;
        int vl = vlen[g]; if (vl == 0) vl = 1;
        const float inv = 1.0f / (float)vl;

#pragma unroll
        for (int fh = 0; fh < 2; ++fh) {
            const int fs = fh * 64 + fs8;
            float acc[8];
#pragma unroll
            for (int i = 0; i < 8; ++i) acc[i] = 0.0f;
#pragma unroll 4
            for (int k = 0; k < KNBR; ++k) {
                const uint4 u = *(const uint4*)(hb + (size_t)ip[k] * HDIM + fs);
                acc[0] += blo(u.x); acc[1] += bhi(u.x);
                acc[2] += blo(u.y); acc[3] += bhi(u.y);
                acc[4] += blo(u.z); acc[5] += bhi(u.z);
                acc[6] += blo(u.w); acc[7] += bhi(u.w);
            }
            unsigned* dst = (unsigned*)(sng + node * LDP + fs);
#pragma unroll
            for (int i = 0; i < 4; ++i) {
                unsigned lo = (unsigned)(unsigned short)f2bf(acc[2 * i] * inv);
                unsigned hi = (unsigned)(unsigned short)f2bf(acc[2 * i + 1] * inv);
                dst[i] = lo | (hi << 16);
            }
            __syncthreads();   // phase alignment keeps L2 working set tight
        }
    }

    // ---- MFMA: acc = NG@W + H@B (one 16-col slice per wave) ----
    const int w = t >> 6, l = t & 63;
    const int m16 = l & 15, quad = l >> 4;
    const int col = w * 16 + m16;

    f32x4 acc[4] = {};
#pragma unroll
    for (int q = 0; q < 4; ++q) {
        const int off = ((q * 4 + quad) * 128 + col) << 3;
        const short8 wfW = *(const short8*)(pwW + off);
        const short8 wfB = *(const short8*)(pwB + off);
#pragma unroll
        for (int mt = 0; mt < 4; ++mt) {
            short8 aN = *(const short8*)(sng + (mt * 16 + m16) * LDP + q * 32 + quad * 8);
            short8 aH = *(const short8*)(h_in + (size_t)(row0 + mt * 16 + m16) * HDIM + q * 32 + quad * 8);
            acc[mt] = __builtin_amdgcn_mfma_f32_16x16x32_bf16(aN, wfW, acc[mt], 0, 0, 0);
            acc[mt] = __builtin_amdgcn_mfma_f32_16x16x32_bf16(aH, wfB, acc[mt], 0, 0, 0);
        }
    }

#pragma unroll
    for (int mt = 0; mt < 4; ++mt)
#pragma unroll
        for (int r = 0; r < 4; ++r) {
            const int rr = row0 + mt * 16 + quad * 4 + r;
            h_out[(size_t)rr * HDIM + col] = __float2bfloat16(fmaxf(acc[mt][r], 0.0f));
        }
}

// ---------------- classifier: softmax(relu(h@W1+b1)@W2 + b2) ----------------
__global__ __launch_bounds__(512, 4) void cls_gemm(const bf16* __restrict__ h,
                                                   const short* __restrict__ pwW1,
                                                   const float* __restrict__ b1,
                                                   const short* __restrict__ pwW2,
                                                   const float* __restrict__ b2,
                                                   float* __restrict__ out) {
    __shared__ short sh[BM * LDP];
    __shared__ short sz[BM * LDP];
    __shared__ float lg[BM * 48];
    const int t = threadIdx.x;
    const int row0 = blockIdx.x * BM;

    {
        const int r = t >> 3, fs = (t & 7) * 16;
        const uint4* p = (const uint4*)(h + (size_t)(row0 + r) * HDIM + fs);
        uint4 a = p[0], b = p[1];
        uint4* d = (uint4*)(sh + r * LDP + fs);
        d[0] = a; d[1] = b;
    }
    __syncthreads();

    const int w = t >> 6, l = t & 63;
    const int m16 = l & 15, quad = l >> 4;
    const int col = w * 16 + m16;

    // ---- stage 1: z = relu(h @ W1 + b1) -> LDS ----
    {
        short8 wf[4];
#pragma unroll
        for (int q = 0; q < 4; ++q)
            wf[q] = *(const short8*)(pwW1 + (((q * 4 + quad) * 128 + col) << 3));
        f32x4 acc[4] = {};
#pragma unroll
        for (int q = 0; q < 4; ++q)
#pragma unroll
            for (int mt = 0; mt < 4; ++mt) {
                short8 a = *(const short8*)(sh + (mt * 16 + m16) * LDP + q * 32 + quad * 8);
                acc[mt] = __builtin_amdgcn_mfma_f32_16x16x32_bf16(a, wf[q], acc[mt], 0, 0, 0);
            }
        const float bias = b1[col];
#pragma unroll
        for (int mt = 0; mt < 4; ++mt)
#pragma unroll
            for (int r = 0; r < 4; ++r)
                sz[(mt * 16 + quad * 4 + r) * LDP + col] = f2bf(fmaxf(acc[mt][r] + bias, 0.0f));
    }
    __syncthreads();

    // ---- stage 2: logits = z @ W2 + b2 (waves 0..2 cover 40 cols) ----
    if (w < 3) {
        const bool valid = (col < NCLS);
        short8 wf[4];
#pragma unroll
        for (int q = 0; q < 4; ++q) {
            if (valid) wf[q] = *(const short8*)(pwW2 + (((q * 4 + quad) * NCLS + col) << 3));
            else {
#pragma unroll
                for (int j = 0; j < 8; ++j) wf[q][j] = 0;
            }
        }
        f32x4 acc[4] = {};
#pragma unroll
        for (int q = 0; q < 4; ++q)
#pragma unroll
            for (int mt = 0; mt < 4; ++mt) {
                short8 a = *(const short8*)(sz + (mt * 16 + m16) * LDP + q * 32 + quad * 8);
                acc[mt] = __builtin_amdgcn_mfma_f32_16x16x32_bf16(a, wf[q], acc[mt], 0, 0, 0);
            }
        if (valid) {
            const float bias = b2[col];
#pragma unroll
            for (int mt = 0; mt < 4; ++mt)
#pragma unroll
                for (int r = 0; r < 4; ++r)
                    lg[(mt * 16 + quad * 4 + r) * 48 + col] = acc[mt][r] + bias;
        }
    }
    __syncthreads();

    // ---- softmax per row ----
    if (t < BM) {
        float* row = lg + t * 48;
        float m = row[0];
        for (int c = 1; c < NCLS; ++c) m = fmaxf(m, row[c]);
        float s = 0.0f;
        for (int c = 0; c < NCLS; ++c) { float e = expf(row[c] - m); row[c] = e; s += e; }
        const float inv = 1.0f / s;
        for (int c = 0; c < NCLS; ++c) row[c] *= inv;
    }
    __syncthreads();

    for (int i = t; i < BM * NCLS; i += 512) {
        const int r = i / NCLS, c = i - r * NCLS;
        out[(size_t)row0 * NCLS + i] = lg[r * 48 + c];
    }
}

extern "C" void kernel_launch(void* const* d_in, const int* in_sizes, int n_in,
                              void* d_out, int out_size, void* d_ws, size_t ws_size,
                              hipStream_t stream) {
    const float* x    = (const float*)d_in[0];
    const int*  nidx  = (const int*)  d_in[1];
    const int*  vlen  = (const int*)  d_in[2];
    const float* Wemb = (const float*)d_in[3];
    const float* gW   = (const float*)d_in[4];
    const float* gB   = (const float*)d_in[5];
    const float* W1   = (const float*)d_in[6];
    const float* b1   = (const float*)d_in[7];
    const float* W2   = (const float*)d_in[8];
    const float* b2   = (const float*)d_in[9];
    float* out = (float*)d_out;

    const int nodes = BATCH * NB;           // 40000
    bf16* h0 = (bf16*)d_ws;
    bf16* h1 = h0 + (size_t)nodes * HDIM;
    short* pw = (short*)(h1 + (size_t)nodes * HDIM);   // 272 KB packed weights
    const short* pwE  = pw;
    const short* pwW1 = pw + 7 * 16384;
    const short* pwW2 = pw + 8 * 16384;

    pack_weights<<<(8 * 16384 + 128 * NCLS + 255) / 256, 256, 0, stream>>>(Wemb, gW, gB, W1, W2, pw);
    embed_gemm<<<NTILES, 512, 0, stream>>>(x, pwE, h0);

    for (int lyr = 0; lyr < NLAYER; ++lyr) {
        layer_gemm<<<LGRID, 512, 0, stream>>>(h0, nidx, vlen,
                                              pw + (size_t)(1 + lyr) * 16384,
                                              pw + (size_t)(4 + lyr) * 16384,
                                              h1);
        bf16* tmp = h0; h0 = h1; h1 = tmp;
    }

    cls_gemm<<<NTILES, 512, 0, stream>>>(h0, pwW1, b1, pwW2, b2, out);
}

// Round 10
// 183.591 us; speedup vs baseline: 1.1126x; 1.1027x over previous
//
#include <hip/hip_runtime.h>
#include <hip/hip_bf16.h>

typedef __hip_bfloat16 bf16;
typedef __attribute__((ext_vector_type(8))) short short8;
typedef __attribute__((ext_vector_type(4))) float f32x4;

#define NB    20000
#define BATCH 2
#define HDIM  128
#define KNBR  32
#define NCLS  40
#define NLAYER 3
#define BM    64          // rows (nodes) per block tile
#define LDP   136         // padded LDS row stride (bf16 elems): 272 B, 16B-aligned
#define NTILES 625        // flattened tiles over 40000 nodes
#define LGRID  632        // 79*8, batch-XCD swizzled with guards

__device__ __forceinline__ short f2bf(float v) {
    return __builtin_bit_cast(short, __float2bfloat16(v));
}
__device__ __forceinline__ float blo(unsigned u) { return __builtin_bit_cast(float, u << 16); }
__device__ __forceinline__ float bhi(unsigned u) { return __builtin_bit_cast(float, u & 0xffff0000u); }

// ---------------- weight pre-pack: f32 [K][N] -> bf16 fragment layout ----------------
__global__ void pack_weights(const float* __restrict__ Wemb, const float* __restrict__ gW,
                             const float* __restrict__ gB, const float* __restrict__ W1,
                             const float* __restrict__ W2, short* __restrict__ pw) {
    const int idx = blockIdx.x * 256 + threadIdx.x;
    if (idx < 8 * 16384) {
        const int m = idx >> 14, e = idx & 16383;
        const float* src = (m == 0) ? Wemb
                         : (m <= 3) ? gW + (size_t)(m - 1) * 16384
                         : (m <= 6) ? gB + (size_t)(m - 4) * 16384
                         : W1;
        const int k = e >> 7, n = e & 127;
        pw[m * 16384 + (((k >> 3) * 128 + n) << 3) + (k & 7)] = f2bf(src[e]);
    } else {
        const int e = idx - 8 * 16384;
        if (e < 128 * NCLS) {
            const int k = e / NCLS, n = e - k * NCLS;
            pw[8 * 16384 + ((k >> 3) * NCLS + n) * 8 + (k & 7)] = f2bf(W2[e]);
        }
    }
}

// ---------------- embed: h0 = (x @ Wemb) / rowsum(x), rowsum via ones-MFMA ----------------
__global__ __launch_bounds__(512, 4) void embed_gemm(const float* __restrict__ x,
                                                     const short* __restrict__ pwE,
                                                     bf16* __restrict__ h0) {
    __shared__ short sx[BM * LDP];
    const int t = threadIdx.x;
    const int row0 = blockIdx.x * BM;

    {
        const int r = t >> 3, fs = (t & 7) * 16;
        const float4* p = (const float4*)(x + (size_t)(row0 + r) * HDIM + fs);
        float4 v[4];
#pragma unroll
        for (int i = 0; i < 4; ++i) v[i] = p[i];
        const float* vf = (const float*)v;
        unsigned* dst = (unsigned*)(sx + r * LDP + fs);
#pragma unroll
        for (int i = 0; i < 8; ++i) {
            unsigned lo = (unsigned)(unsigned short)f2bf(vf[2 * i]);
            unsigned hi = (unsigned)(unsigned short)f2bf(vf[2 * i + 1]);
            dst[i] = lo | (hi << 16);
        }
    }
    __syncthreads();

    const int w = t >> 6, l = t & 63;
    const int m16 = l & 15, quad = l >> 4;
    const int col = w * 16 + m16;

    short8 ones;
#pragma unroll
    for (int j = 0; j < 8; ++j) ones[j] = (short)0x3F80;  // bf16 1.0

    short8 wf[4];
#pragma unroll
    for (int q = 0; q < 4; ++q)
        wf[q] = *(const short8*)(pwE + (((q * 4 + quad) * 128 + col) << 3));

    f32x4 acc[4] = {}, rsum[4] = {};
#pragma unroll
    for (int q = 0; q < 4; ++q)
#pragma unroll
        for (int mt = 0; mt < 4; ++mt) {
            short8 a = *(const short8*)(sx + (mt * 16 + m16) * LDP + q * 32 + quad * 8);
            acc[mt]  = __builtin_amdgcn_mfma_f32_16x16x32_bf16(a, wf[q], acc[mt], 0, 0, 0);
            rsum[mt] = __builtin_amdgcn_mfma_f32_16x16x32_bf16(a, ones,  rsum[mt], 0, 0, 0);
        }

#pragma unroll
    for (int mt = 0; mt < 4; ++mt)
#pragma unroll
        for (int r = 0; r < 4; ++r) {
            const int rr = row0 + mt * 16 + quad * 4 + r;
            h0[(size_t)rr * HDIM + col] = __float2bfloat16(acc[mt][r] / rsum[mt][r]);
        }
}

// ---------------- GCN layer: h_out = relu(NG@W + H@B) ----------------
// r7 structure ((512,4), sh staging, upfront weight frags) with ONE change:
// the gather k-loop is software-pipelined 4-ahead (8 loads in flight).
__global__ __launch_bounds__(512, 4) void layer_gemm(const bf16* __restrict__ h_in,
                                                     const int* __restrict__ nidx,
                                                     const int* __restrict__ vlen,
                                                     const short* __restrict__ pwW,
                                                     const short* __restrict__ pwB,
                                                     bf16* __restrict__ h_out) {
    __shared__ int   sidx[BM * KNBR];   // 8 KB
    __shared__ short sng[BM * LDP];     // 17.4 KB
    __shared__ short sh[BM * LDP];      // 17.4 KB

    const int slot = blockIdx.x & 7;
    const int half = slot >> 2;
    const int idx  = (blockIdx.x >> 3) * 4 + (slot & 3);
    int tile;
    if (half == 0) { if (idx > 312) return; tile = idx; }
    else           { if (idx > 311) return; tile = idx + 313; }

    const int t = threadIdx.x;
    const int row0 = tile * BM;

    ((int4*)sidx)[t] = ((const int4*)(nidx + (size_t)row0 * KNBR))[t];
    {
        const int r = t >> 3, fs = (t & 7) * 16;
        const uint4* p = (const uint4*)(h_in + (size_t)(row0 + r) * HDIM + fs);
        uint4 a = p[0], b = p[1];
        uint4* d = (uint4*)(sh + r * LDP + fs);
        d[0] = a; d[1] = b;
    }
    __syncthreads();

    // ---- gather: 8 threads/node, 8 features, 2 phases, 4-ahead pipeline ----
    {
        const int node = t >> 3;
        const int fs8 = (t & 7) * 8;
        const int g = row0 + node;
        const bf16* hb = h_in + (size_t)((g >= NB) ? NB : 0) * HDIM;
        const int* ip = sidx + node * KNBR;
        int vl = vlen[g]; if (vl == 0) vl = 1;
        const float inv = 1.0f / (float)vl;

#pragma unroll
        for (int fh = 0; fh < 2; ++fh) {
            const int fs = fh * 64 + fs8;
            float acc[8];
#pragma unroll
            for (int i = 0; i < 8; ++i) acc[i] = 0.0f;

            uint4 u[4], v[4];
#pragma unroll
            for (int j = 0; j < 4; ++j)
                u[j] = *(const uint4*)(hb + (size_t)ip[j] * HDIM + fs);
#pragma unroll
            for (int kb = 0; kb < KNBR; kb += 4) {
                if (kb + 4 < KNBR) {
#pragma unroll
                    for (int j = 0; j < 4; ++j)
                        v[j] = *(const uint4*)(hb + (size_t)ip[kb + 4 + j] * HDIM + fs);
                }
#pragma unroll
                for (int j = 0; j < 4; ++j) {
                    const uint4 uu = u[j];
                    acc[0] += blo(uu.x); acc[1] += bhi(uu.x);
                    acc[2] += blo(uu.y); acc[3] += bhi(uu.y);
                    acc[4] += blo(uu.z); acc[5] += bhi(uu.z);
                    acc[6] += blo(uu.w); acc[7] += bhi(uu.w);
                }
#pragma unroll
                for (int j = 0; j < 4; ++j) u[j] = v[j];
            }

            unsigned* dst = (unsigned*)(sng + node * LDP + fs);
#pragma unroll
            for (int i = 0; i < 4; ++i) {
                unsigned lo = (unsigned)(unsigned short)f2bf(acc[2 * i] * inv);
                unsigned hi = (unsigned)(unsigned short)f2bf(acc[2 * i + 1] * inv);
                dst[i] = lo | (hi << 16);
            }
            __syncthreads();   // phase alignment keeps L2 working set tight
        }
    }

    // ---- MFMA: acc = NG@W + H@B (one 16-col slice per wave) ----
    const int w = t >> 6, l = t & 63;
    const int m16 = l & 15, quad = l >> 4;
    const int col = w * 16 + m16;

    short8 wfW[4], wfB[4];
#pragma unroll
    for (int q = 0; q < 4; ++q) {
        const int off = ((q * 4 + quad) * 128 + col) << 3;
        wfW[q] = *(const short8*)(pwW + off);
        wfB[q] = *(const short8*)(pwB + off);
    }

    f32x4 acc[4] = {};
#pragma unroll
    for (int q = 0; q < 4; ++q)
#pragma unroll
        for (int mt = 0; mt < 4; ++mt) {
            short8 aN = *(const short8*)(sng + (mt * 16 + m16) * LDP + q * 32 + quad * 8);
            short8 aH = *(const short8*)(sh  + (mt * 16 + m16) * LDP + q * 32 + quad * 8);
            acc[mt] = __builtin_amdgcn_mfma_f32_16x16x32_bf16(aN, wfW[q], acc[mt], 0, 0, 0);
            acc[mt] = __builtin_amdgcn_mfma_f32_16x16x32_bf16(aH, wfB[q], acc[mt], 0, 0, 0);
        }

#pragma unroll
    for (int mt = 0; mt < 4; ++mt)
#pragma unroll
        for (int r = 0; r < 4; ++r) {
            const int rr = row0 + mt * 16 + quad * 4 + r;
            h_out[(size_t)rr * HDIM + col] = __float2bfloat16(fmaxf(acc[mt][r], 0.0f));
        }
}

// ---------------- classifier: softmax(relu(h@W1+b1)@W2 + b2) ----------------
__global__ __launch_bounds__(512, 4) void cls_gemm(const bf16* __restrict__ h,
                                                   const short* __restrict__ pwW1,
                                                   const float* __restrict__ b1,
                                                   const short* __restrict__ pwW2,
                                                   const float* __restrict__ b2,
                                                   float* __restrict__ out) {
    __shared__ short sh[BM * LDP];
    __shared__ short sz[BM * LDP];
    __shared__ float lg[BM * 48];
    const int t = threadIdx.x;
    const int row0 = blockIdx.x * BM;

    {
        const int r = t >> 3, fs = (t & 7) * 16;
        const uint4* p = (const uint4*)(h + (size_t)(row0 + r) * HDIM + fs);
        uint4 a = p[0], b = p[1];
        uint4* d = (uint4*)(sh + r * LDP + fs);
        d[0] = a; d[1] = b;
    }
    __syncthreads();

    const int w = t >> 6, l = t & 63;
    const int m16 = l & 15, quad = l >> 4;
    const int col = w * 16 + m16;

    // ---- stage 1: z = relu(h @ W1 + b1) -> LDS ----
    {
        short8 wf[4];
#pragma unroll
        for (int q = 0; q < 4; ++q)
            wf[q] = *(const short8*)(pwW1 + (((q * 4 + quad) * 128 + col) << 3));
        f32x4 acc[4] = {};
#pragma unroll
        for (int q = 0; q < 4; ++q)
#pragma unroll
            for (int mt = 0; mt < 4; ++mt) {
                short8 a = *(const short8*)(sh + (mt * 16 + m16) * LDP + q * 32 + quad * 8);
                acc[mt] = __builtin_amdgcn_mfma_f32_16x16x32_bf16(a, wf[q], acc[mt], 0, 0, 0);
            }
        const float bias = b1[col];
#pragma unroll
        for (int mt = 0; mt < 4; ++mt)
#pragma unroll
            for (int r = 0; r < 4; ++r)
                sz[(mt * 16 + quad * 4 + r) * LDP + col] = f2bf(fmaxf(acc[mt][r] + bias, 0.0f));
    }
    __syncthreads();

    // ---- stage 2: logits = z @ W2 + b2 (waves 0..2 cover 40 cols) ----
    if (w < 3) {
        const bool valid = (col < NCLS);
        short8 wf[4];
#pragma unroll
        for (int q = 0; q < 4; ++q) {
            if (valid) wf[q] = *(const short8*)(pwW2 + (((q * 4 + quad) * NCLS + col) << 3));
            else {
#pragma unroll
                for (int j = 0; j < 8; ++j) wf[q][j] = 0;
            }
        }
        f32x4 acc[4] = {};
#pragma unroll
        for (int q = 0; q < 4; ++q)
#pragma unroll
            for (int mt = 0; mt < 4; ++mt) {
                short8 a = *(const short8*)(sz + (mt * 16 + m16) * LDP + q * 32 + quad * 8);
                acc[mt] = __builtin_amdgcn_mfma_f32_16x16x32_bf16(a, wf[q], acc[mt], 0, 0, 0);
            }
        if (valid) {
            const float bias = b2[col];
#pragma unroll
            for (int mt = 0; mt < 4; ++mt)
#pragma unroll
                for (int r = 0; r < 4; ++r)
                    lg[(mt * 16 + quad * 4 + r) * 48 + col] = acc[mt][r] + bias;
        }
    }
    __syncthreads();

    // ---- softmax per row ----
    if (t < BM) {
        float* row = lg + t * 48;
        float m = row[0];
        for (int c = 1; c < NCLS; ++c) m = fmaxf(m, row[c]);
        float s = 0.0f;
        for (int c = 0; c < NCLS; ++c) { float e = expf(row[c] - m); row[c] = e; s += e; }
        const float inv = 1.0f / s;
        for (int c = 0; c < NCLS; ++c) row[c] *= inv;
    }
    __syncthreads();

    for (int i = t; i < BM * NCLS; i += 512) {
        const int r = i / NCLS, c = i - r * NCLS;
        out[(size_t)row0 * NCLS + i] = lg[r * 48 + c];
    }
}

extern "C" void kernel_launch(void* const* d_in, const int* in_sizes, int n_in,
                              void* d_out, int out_size, void* d_ws, size_t ws_size,
                              hipStream_t stream) {
    const float* x    = (const float*)d_in[0];
    const int*  nidx  = (const int*)  d_in[1];
    const int*  vlen  = (const int*)  d_in[2];
    const float* Wemb = (const float*)d_in[3];
    const float* gW   = (const float*)d_in[4];
    const float* gB   = (const float*)d_in[5];
    const float* W1   = (const float*)d_in[6];
    const float* b1   = (const float*)d_in[7];
    const float* W2   = (const float*)d_in[8];
    const float* b2   = (const float*)d_in[9];
    float* out = (float*)d_out;

    const int nodes = BATCH * NB;           // 40000
    bf16* h0 = (bf16*)d_ws;
    bf16* h1 = h0 + (size_t)nodes * HDIM;
    short* pw = (short*)(h1 + (size_t)nodes * HDIM);   // 272 KB packed weights
    const short* pwE  = pw;
    const short* pwW1 = pw + 7 * 16384;
    const short* pwW2 = pw + 8 * 16384;

    pack_weights<<<(8 * 16384 + 128 * NCLS + 255) / 256, 256, 0, stream>>>(Wemb, gW, gB, W1, W2, pw);
    embed_gemm<<<NTILES, 512, 0, stream>>>(x, pwE, h0);

    for (int lyr = 0; lyr < NLAYER; ++lyr) {
        layer_gemm<<<LGRID, 512, 0, stream>>>(h0, nidx, vlen,
                                              pw + (size_t)(1 + lyr) * 16384,
                                              pw + (size_t)(4 + lyr) * 16384,
                                              h1);
        bf16* tmp = h0; h0 = h1; h1 = tmp;
    }

    cls_gemm<<<NTILES, 512, 0, stream>>>(h0, pwW1, b1, pwW2, b2, out);
}

// Round 11
// 169.480 us; speedup vs baseline: 1.2053x; 1.0833x over previous
//
#include <hip/hip_runtime.h>
#include <hip/hip_bf16.h>

typedef __hip_bfloat16 bf16;
typedef __attribute__((ext_vector_type(8))) short short8;
typedef __attribute__((ext_vector_type(4))) float f32x4;

#define NB    20000
#define BATCH 2
#define HDIM  128
#define KNBR  32
#define NCLS  40
#define NLAYER 3
#define BM    64          // rows per tile: embed/cls kernels
#define LBM   32          // rows per tile: layer kernel (4 blocks/CU)
#define LDP   136         // padded LDS row stride (bf16 elems): 272 B, 16B-aligned
#define NTILES 625        // 64-row tiles over 40000 nodes (embed/cls)
#define LTPH   625        // 32-row layer tiles per batch half (20000/32, exact)
#define LGRID  1256       // 8*157, batch-XCD swizzled with guards

__device__ __forceinline__ short f2bf(float v) {
    return __builtin_bit_cast(short, __float2bfloat16(v));
}
__device__ __forceinline__ float blo(unsigned u) { return __builtin_bit_cast(float, u << 16); }
__device__ __forceinline__ float bhi(unsigned u) { return __builtin_bit_cast(float, u & 0xffff0000u); }

// ---------------- weight pre-pack: f32 [K][N] -> bf16 fragment layout ----------------
__global__ void pack_weights(const float* __restrict__ Wemb, const float* __restrict__ gW,
                             const float* __restrict__ gB, const float* __restrict__ W1,
                             const float* __restrict__ W2, short* __restrict__ pw) {
    const int idx = blockIdx.x * 256 + threadIdx.x;
    if (idx < 8 * 16384) {
        const int m = idx >> 14, e = idx & 16383;
        const float* src = (m == 0) ? Wemb
                         : (m <= 3) ? gW + (size_t)(m - 1) * 16384
                         : (m <= 6) ? gB + (size_t)(m - 4) * 16384
                         : W1;
        const int k = e >> 7, n = e & 127;
        pw[m * 16384 + (((k >> 3) * 128 + n) << 3) + (k & 7)] = f2bf(src[e]);
    } else {
        const int e = idx - 8 * 16384;
        if (e < 128 * NCLS) {
            const int k = e / NCLS, n = e - k * NCLS;
            pw[8 * 16384 + ((k >> 3) * NCLS + n) * 8 + (k & 7)] = f2bf(W2[e]);
        }
    }
}

// ---------------- embed: h0 = (x @ Wemb) / rowsum(x), rowsum via ones-MFMA ----------------
__global__ __launch_bounds__(512, 4) void embed_gemm(const float* __restrict__ x,
                                                     const short* __restrict__ pwE,
                                                     bf16* __restrict__ h0) {
    __shared__ short sx[BM * LDP];
    const int t = threadIdx.x;
    const int row0 = blockIdx.x * BM;

    {
        const int r = t >> 3, fs = (t & 7) * 16;
        const float4* p = (const float4*)(x + (size_t)(row0 + r) * HDIM + fs);
        float4 v[4];
#pragma unroll
        for (int i = 0; i < 4; ++i) v[i] = p[i];
        const float* vf = (const float*)v;
        unsigned* dst = (unsigned*)(sx + r * LDP + fs);
#pragma unroll
        for (int i = 0; i < 8; ++i) {
            unsigned lo = (unsigned)(unsigned short)f2bf(vf[2 * i]);
            unsigned hi = (unsigned)(unsigned short)f2bf(vf[2 * i + 1]);
            dst[i] = lo | (hi << 16);
        }
    }
    __syncthreads();

    const int w = t >> 6, l = t & 63;
    const int m16 = l & 15, quad = l >> 4;
    const int col = w * 16 + m16;

    short8 ones;
#pragma unroll
    for (int j = 0; j < 8; ++j) ones[j] = (short)0x3F80;  // bf16 1.0

    short8 wf[4];
#pragma unroll
    for (int q = 0; q < 4; ++q)
        wf[q] = *(const short8*)(pwE + (((q * 4 + quad) * 128 + col) << 3));

    f32x4 acc[4] = {}, rsum[4] = {};
#pragma unroll
    for (int q = 0; q < 4; ++q)
#pragma unroll
        for (int mt = 0; mt < 4; ++mt) {
            short8 a = *(const short8*)(sx + (mt * 16 + m16) * LDP + q * 32 + quad * 8);
            acc[mt]  = __builtin_amdgcn_mfma_f32_16x16x32_bf16(a, wf[q], acc[mt], 0, 0, 0);
            rsum[mt] = __builtin_amdgcn_mfma_f32_16x16x32_bf16(a, ones,  rsum[mt], 0, 0, 0);
        }

#pragma unroll
    for (int mt = 0; mt < 4; ++mt)
#pragma unroll
        for (int r = 0; r < 4; ++r) {
            const int rr = row0 + mt * 16 + quad * 4 + r;
            h0[(size_t)rr * HDIM + col] = __float2bfloat16(acc[mt][r] / rsum[mt][r]);
        }
}

// ---------------- GCN layer: h_out = relu(NG@W + H@B) ----------------
// r7 structure, ONE change: LBM=32 rows / 256 threads -> 21.4 KB LDS ->
// 4 independent blocks/CU (was 2).  Sync drains and gather phases of
// different blocks overlap; 625 tiles per batch half exactly (no straddle).
__global__ __launch_bounds__(256, 4) void layer_gemm(const bf16* __restrict__ h_in,
                                                     const int* __restrict__ nidx,
                                                     const int* __restrict__ vlen,
                                                     const short* __restrict__ pwW,
                                                     const short* __restrict__ pwB,
                                                     bf16* __restrict__ h_out) {
    __shared__ int   sidx[LBM * KNBR];   // 4 KB
    __shared__ short sng[LBM * LDP];     // 8.7 KB
    __shared__ short sh[LBM * LDP];      // 8.7 KB

    const int slot = blockIdx.x & 7;
    const int half = slot >> 2;
    const int idx  = (blockIdx.x >> 3) * 4 + (slot & 3);
    if (idx >= LTPH) return;
    const int tile = half * LTPH + idx;

    const int t = threadIdx.x;
    const int row0 = tile * LBM;

    // stage neighbor indices (1024 ints via int4) + own h tile (bf16 copy)
    ((int4*)sidx)[t] = ((const int4*)(nidx + (size_t)row0 * KNBR))[t];
    {
        const int r = t >> 3, fs = (t & 7) * 16;
        const uint4* p = (const uint4*)(h_in + (size_t)(row0 + r) * HDIM + fs);
        uint4 a = p[0], b = p[1];
        uint4* d = (uint4*)(sh + r * LDP + fs);
        d[0] = a; d[1] = b;
    }
    __syncthreads();

    // ---- gather: 8 threads/node, 8 features, 2 phases (r7 inner loop) ----
    {
        const int node = t >> 3;
        const int fs8 = (t & 7) * 8;
        const int g = row0 + node;
        const bf16* hb = h_in + (size_t)((g >= NB) ? NB : 0) * HDIM;
        const int* ip = sidx + node * KNBR;
        int vl = vlen[g]; if (vl == 0) vl = 1;
        const float inv = 1.0f / (float)vl;

#pragma unroll
        for (int fh = 0; fh < 2; ++fh) {
            const int fs = fh * 64 + fs8;
            float acc[8];
#pragma unroll
            for (int i = 0; i < 8; ++i) acc[i] = 0.0f;
#pragma unroll 4
            for (int k = 0; k < KNBR; ++k) {
                const uint4 u = *(const uint4*)(hb + (size_t)ip[k] * HDIM + fs);
                acc[0] += blo(u.x); acc[1] += bhi(u.x);
                acc[2] += blo(u.y); acc[3] += bhi(u.y);
                acc[4] += blo(u.z); acc[5] += bhi(u.z);
                acc[6] += blo(u.w); acc[7] += bhi(u.w);
            }
            unsigned* dst = (unsigned*)(sng + node * LDP + fs);
#pragma unroll
            for (int i = 0; i < 4; ++i) {
                unsigned lo = (unsigned)(unsigned short)f2bf(acc[2 * i] * inv);
                unsigned hi = (unsigned)(unsigned short)f2bf(acc[2 * i + 1] * inv);
                dst[i] = lo | (hi << 16);
            }
            __syncthreads();   // phase alignment keeps L2 working set tight
        }
    }

    // ---- MFMA: acc = NG@W + H@B (wave w covers cols w*32..w*32+31) ----
    const int w = t >> 6, l = t & 63;
    const int m16 = l & 15, quad = l >> 4;
    const int ncol0 = w * 32;

    short8 wfW[2][4], wfB[2][4];
#pragma unroll
    for (int nt = 0; nt < 2; ++nt) {
        const int col = ncol0 + nt * 16 + m16;
#pragma unroll
        for (int q = 0; q < 4; ++q) {
            const int off = ((q * 4 + quad) * 128 + col) << 3;
            wfW[nt][q] = *(const short8*)(pwW + off);
            wfB[nt][q] = *(const short8*)(pwB + off);
        }
    }

    f32x4 acc[2][2] = {};
#pragma unroll
    for (int q = 0; q < 4; ++q)
#pragma unroll
        for (int mt = 0; mt < 2; ++mt) {
            short8 aN = *(const short8*)(sng + (mt * 16 + m16) * LDP + q * 32 + quad * 8);
            short8 aH = *(const short8*)(sh  + (mt * 16 + m16) * LDP + q * 32 + quad * 8);
#pragma unroll
            for (int nt = 0; nt < 2; ++nt) {
                acc[mt][nt] = __builtin_amdgcn_mfma_f32_16x16x32_bf16(aN, wfW[nt][q], acc[mt][nt], 0, 0, 0);
                acc[mt][nt] = __builtin_amdgcn_mfma_f32_16x16x32_bf16(aH, wfB[nt][q], acc[mt][nt], 0, 0, 0);
            }
        }

#pragma unroll
    for (int mt = 0; mt < 2; ++mt)
#pragma unroll
        for (int nt = 0; nt < 2; ++nt)
#pragma unroll
            for (int r = 0; r < 4; ++r) {
                const int rr = row0 + mt * 16 + quad * 4 + r;
                const int cc = ncol0 + nt * 16 + m16;
                h_out[(size_t)rr * HDIM + cc] = __float2bfloat16(fmaxf(acc[mt][nt][r], 0.0f));
            }
}

// ---------------- classifier: softmax(relu(h@W1+b1)@W2 + b2) ----------------
__global__ __launch_bounds__(512, 4) void cls_gemm(const bf16* __restrict__ h,
                                                   const short* __restrict__ pwW1,
                                                   const float* __restrict__ b1,
                                                   const short* __restrict__ pwW2,
                                                   const float* __restrict__ b2,
                                                   float* __restrict__ out) {
    __shared__ short sh[BM * LDP];
    __shared__ short sz[BM * LDP];
    __shared__ float lg[BM * 48];
    const int t = threadIdx.x;
    const int row0 = blockIdx.x * BM;

    {
        const int r = t >> 3, fs = (t & 7) * 16;
        const uint4* p = (const uint4*)(h + (size_t)(row0 + r) * HDIM + fs);
        uint4 a = p[0], b = p[1];
        uint4* d = (uint4*)(sh + r * LDP + fs);
        d[0] = a; d[1] = b;
    }
    __syncthreads();

    const int w = t >> 6, l = t & 63;
    const int m16 = l & 15, quad = l >> 4;
    const int col = w * 16 + m16;

    // ---- stage 1: z = relu(h @ W1 + b1) -> LDS ----
    {
        short8 wf[4];
#pragma unroll
        for (int q = 0; q < 4; ++q)
            wf[q] = *(const short8*)(pwW1 + (((q * 4 + quad) * 128 + col) << 3));
        f32x4 acc[4] = {};
#pragma unroll
        for (int q = 0; q < 4; ++q)
#pragma unroll
            for (int mt = 0; mt < 4; ++mt) {
                short8 a = *(const short8*)(sh + (mt * 16 + m16) * LDP + q * 32 + quad * 8);
                acc[mt] = __builtin_amdgcn_mfma_f32_16x16x32_bf16(a, wf[q], acc[mt], 0, 0, 0);
            }
        const float bias = b1[col];
#pragma unroll
        for (int mt = 0; mt < 4; ++mt)
#pragma unroll
            for (int r = 0; r < 4; ++r)
                sz[(mt * 16 + quad * 4 + r) * LDP + col] = f2bf(fmaxf(acc[mt][r] + bias, 0.0f));
    }
    __syncthreads();

    // ---- stage 2: logits = z @ W2 + b2 (waves 0..2 cover 40 cols) ----
    if (w < 3) {
        const bool valid = (col < NCLS);
        short8 wf[4];
#pragma unroll
        for (int q = 0; q < 4; ++q) {
            if (valid) wf[q] = *(const short8*)(pwW2 + (((q * 4 + quad) * NCLS + col) << 3));
            else {
#pragma unroll
                for (int j = 0; j < 8; ++j) wf[q][j] = 0;
            }
        }
        f32x4 acc[4] = {};
#pragma unroll
        for (int q = 0; q < 4; ++q)
#pragma unroll
            for (int mt = 0; mt < 4; ++mt) {
                short8 a = *(const short8*)(sz + (mt * 16 + m16) * LDP + q * 32 + quad * 8);
                acc[mt] = __builtin_amdgcn_mfma_f32_16x16x32_bf16(a, wf[q], acc[mt], 0, 0, 0);
            }
        if (valid) {
            const float bias = b2[col];
#pragma unroll
            for (int mt = 0; mt < 4; ++mt)
#pragma unroll
                for (int r = 0; r < 4; ++r)
                    lg[(mt * 16 + quad * 4 + r) * 48 + col] = acc[mt][r] + bias;
        }
    }
    __syncthreads();

    // ---- softmax per row ----
    if (t < BM) {
        float* row = lg + t * 48;
        float m = row[0];
        for (int c = 1; c < NCLS; ++c) m = fmaxf(m, row[c]);
        float s = 0.0f;
        for (int c = 0; c < NCLS; ++c) { float e = expf(row[c] - m); row[c] = e; s += e; }
        const float inv = 1.0f / s;
        for (int c = 0; c < NCLS; ++c) row[c] *= inv;
    }
    __syncthreads();

    for (int i = t; i < BM * NCLS; i += 512) {
        const int r = i / NCLS, c = i - r * NCLS;
        out[(size_t)row0 * NCLS + i] = lg[r * 48 + c];
    }
}

extern "C" void kernel_launch(void* const* d_in, const int* in_sizes, int n_in,
                              void* d_out, int out_size, void* d_ws, size_t ws_size,
                              hipStream_t stream) {
    const float* x    = (const float*)d_in[0];
    const int*  nidx  = (const int*)  d_in[1];
    const int*  vlen  = (const int*)  d_in[2];
    const float* Wemb = (const float*)d_in[3];
    const float* gW   = (const float*)d_in[4];
    const float* gB   = (const float*)d_in[5];
    const float* W1   = (const float*)d_in[6];
    const float* b1   = (const float*)d_in[7];
    const float* W2   = (const float*)d_in[8];
    const float* b2   = (const float*)d_in[9];
    float* out = (float*)d_out;

    const int nodes = BATCH * NB;           // 40000
    bf16* h0 = (bf16*)d_ws;
    bf16* h1 = h0 + (size_t)nodes * HDIM;
    short* pw = (short*)(h1 + (size_t)nodes * HDIM);   // 272 KB packed weights
    const short* pwE  = pw;
    const short* pwW1 = pw + 7 * 16384;
    const short* pwW2 = pw + 8 * 16384;

    pack_weights<<<(8 * 16384 + 128 * NCLS + 255) / 256, 256, 0, stream>>>(Wemb, gW, gB, W1, W2, pw);
    embed_gemm<<<NTILES, 512, 0, stream>>>(x, pwE, h0);

    for (int lyr = 0; lyr < NLAYER; ++lyr) {
        layer_gemm<<<LGRID, 256, 0, stream>>>(h0, nidx, vlen,
                                              pw + (size_t)(1 + lyr) * 16384,
                                              pw + (size_t)(4 + lyr) * 16384,
                                              h1);
        bf16* tmp = h0; h0 = h1; h1 = tmp;
    }

    cls_gemm<<<NTILES, 512, 0, stream>>>(h0, pwW1, b1, pwW2, b2, out);
}